// Round 13
// baseline (285.553 us; speedup 1.0000x reference)
//
#include <hip/hip_runtime.h>
#include <hip/hip_bf16.h>

#define NROWS 65536   // B*H*W*n
#define DIM   512
#define SCALE_ 0.125f // 64^-0.5

typedef short bf16x8 __attribute__((ext_vector_type(8)));
typedef unsigned short u16x8 __attribute__((ext_vector_type(8)));
typedef float f32x4 __attribute__((ext_vector_type(4)));

__device__ __forceinline__ unsigned short f2bf(float f) {
  union { float f; unsigned u; } v; v.f = f;
  unsigned r = v.u + 0x7FFFu + ((v.u >> 16) & 1u);  // RNE
  return (unsigned short)(r >> 16);
}

// async global->LDS, 16B per lane. LDS dest is wave-uniform base + lane*16 (HW).
#define GLL16(gptr, lptr) \
  __builtin_amdgcn_global_load_lds((const __attribute__((address_space(1))) void*)(gptr), \
                                   (__attribute__((address_space(3))) void*)(lptr), 16, 0, 0)
#define VMCNT(n) asm volatile("s_waitcnt vmcnt(" #n ")" ::: "memory")
#define LGKM0    asm volatile("s_waitcnt lgkmcnt(0)" ::: "memory")

// ---------------- prep: weights transpose+convert only (x handled inside K1) ----------------
__global__ void prep_w_kernel(const float* __restrict__ wqkv,
                              const float* __restrict__ wout,
                              unsigned short* __restrict__ wqkvT,
                              unsigned short* __restrict__ woutT) {
  int idx = blockIdx.x * 256 + threadIdx.x;
  if (idx < 1536 * 512) {
    int j = idx >> 9, c = idx & 511;
    wqkvT[idx] = f2bf(wqkv[(size_t)c * 1536 + j]);
  } else {
    int k2 = idx - 1536 * 512;
    int n = k2 >> 9, c = k2 & 511;
    woutT[k2] = f2bf(wout[(size_t)c * 512 + n]);
  }
}

// ---------------- K1: fused QKV GEMM + attention ----------------
// grid 4096 = 512 mtiles x 8 heads. 256 thr (4 waves 2x2), tile 128x192, BK=32.
// A staged as RAW F32 from x via global_load_lds (no prep pass for x);
// converted f32->bf16 at fragment-load time (hides under LDS/stall slack).
// B bf16 from wqkvT. Counted vmcnt(7)/iter (7 GLL per wave: 4 A-f32 + 3 B),
// lgkmcnt(0) before end barrier (proven race fix).
__global__ __launch_bounds__(256, 2)
void qkv_attn_kernel(const float* __restrict__ x,
                     const float* __restrict__ mask,
                     const unsigned short* __restrict__ wqkvT,
                     unsigned short* __restrict__ attn_out) {
  // GEMM buf i at i*28672: A-f32 [128][32] 16KB @0 | B-bf16 [192][32] 12KB @16384.
  // dbuf = 57344. Epilogue union (after loop): Qs[128][64]swz @0 | Ks @16384 |
  // VT[64][152] @32768 | Pl @52224..62464.
  __shared__ __align__(16) unsigned char smem[62464];

  const int t = threadIdx.x;
  const int lane = t & 63, wave = t >> 6;
  const int wm = wave >> 1, wn = wave & 1;
  const int fr = lane & 15, fq = lane >> 4;
  // A stage swizzle (128B f32 rows, 8x16B slots): LDS[row][s] = src[row][s ^ (row&7)]
  const int aswz = ((lane & 7) ^ ((lane >> 3) & 7)) * 4;   // f32 units
  // B stage swizzle (64B bf16 rows, 4x16B slots): sigma(r) = (r&3)^((r>>2)&3)
  const int bswz = ((lane & 3) ^ (((lane >> 2) & 3) ^ ((lane >> 4) & 3))) * 8;  // bf16 units
  const unsigned bsig = ((unsigned)((fr & 3) ^ ((fr >> 2) & 3))) << 4;  // read-side, bytes

  const int per = gridDim.x >> 3;
  const int lin = (blockIdx.x & 7) * per + (blockIdx.x >> 3);
  const int mtile = lin >> 3, head = lin & 7;
  const int r0 = mtile * 128;

  f32x4 acc[4][6];
  const f32x4 z4 = {0.f, 0.f, 0.f, 0.f};
  #pragma unroll
  for (int m = 0; m < 4; ++m)
    #pragma unroll
    for (int n = 0; n < 6; ++n) acc[m][n] = z4;

  auto STAGE = [&](int buf, int kt2) {   // exactly 7 GLL per wave (4 A-f32 + 3 B)
    unsigned char* base = smem + buf * 28672;
    const int k0 = kt2 * 32;
    // A: 16 chunks of 8 f32-rows (1KB); lane covers row lane>>3, 16B-slot lane&7
    const float* gA = x + (size_t)(r0 + (lane >> 3)) * 512 + k0 + aswz;
    #pragma unroll
    for (int i = 0; i < 4; ++i) {
      int c = wave * 4 + i;
      GLL16(gA + (size_t)c * 8 * 512, base + c * 1024);
    }
    // B: 12 chunks of 16 bf16-rows (1KB); lane covers row lane>>2, 16B-slot lane&3
    const unsigned short* gB = wqkvT + k0 + bswz;
    #pragma unroll
    for (int i = 0; i < 3; ++i) {
      int c = wave * 3 + i;
      int n = c * 16 + (lane >> 2);
      int jg = ((n >> 6) << 9) + head * 64 + (n & 63);
      GLL16(gB + (size_t)jg * 512, base + 16384 + c * 1024);
    }
  };

  auto COMPUTE = [&](int buf) {          // 8 f32-b128 + 6 bf16-b128 reads, 24 MFMA
    unsigned char* Ab = smem + buf * 28672;
    unsigned char* Bb = Ab + 16384;
    bf16x8 a[4], b[6];
    #pragma unroll
    for (int m = 0; m < 4; ++m) {
      unsigned row = (unsigned)(wm * 64 + m * 16 + fr);
      unsigned rb = row * 128;
      unsigned s0 = ((unsigned)(2 * fq) ^ (row & 7)) * 16;
      unsigned s1 = s0 ^ 16;                      // (2fq+1)^(row&7) = s0^1 slots
      float4 lo = *(const float4*)(Ab + rb + s0);
      float4 hi = *(const float4*)(Ab + rb + s1);
      u16x8 p;
      p[0] = f2bf(lo.x); p[1] = f2bf(lo.y); p[2] = f2bf(lo.z); p[3] = f2bf(lo.w);
      p[4] = f2bf(hi.x); p[5] = f2bf(hi.y); p[6] = f2bf(hi.z); p[7] = f2bf(hi.w);
      union { u16x8 u; bf16x8 s; } cv; cv.u = p; a[m] = cv.s;
    }
    #pragma unroll
    for (int n = 0; n < 6; ++n)
      b[n] = *(const bf16x8*)(Bb + (unsigned)(wn * 96 + n * 16 + fr) * 64 +
                              (((unsigned)fq << 4) ^ bsig));
    __builtin_amdgcn_s_setprio(1);
    #pragma unroll
    for (int m = 0; m < 4; ++m)
      #pragma unroll
      for (int n = 0; n < 6; ++n)
        acc[m][n] = __builtin_amdgcn_mfma_f32_16x16x32_bf16(a[m], b[n], acc[m][n], 0, 0, 0);
    __builtin_amdgcn_s_setprio(0);
  };

  STAGE(0, 0);
  for (int kt = 0; kt < 16; ++kt) {
    const int cur = kt & 1;
    if (kt < 15) {
      STAGE(cur ^ 1, kt + 1);   // 7 newer ops in flight...
      VMCNT(7);                 // ...retires exactly tile kt's 7
    } else {
      VMCNT(0);
    }
    __builtin_amdgcn_s_barrier();      // publish tile kt block-wide
    COMPUTE(cur);
    LGKM0;                             // all ds_reads retired (regs latched)...
    __builtin_amdgcn_s_barrier();      // ...before any wave overwrites this buffer
  }
  __builtin_amdgcn_sched_barrier(0);   // keep epilogue vmem out of the counted loop

  // ---------------- epilogue (proven structure, unchanged) ----------------
  unsigned short* Qs = (unsigned short*)smem;             // [128][64] bf16, XOR-swz
  unsigned short* Ks = (unsigned short*)(smem + 16384);   // [128][64]
  unsigned short* VT = (unsigned short*)(smem + 32768);   // [64][152]: V^T, cols128..143 zero
  unsigned short* Pl = (unsigned short*)(smem + 52224);   // [8][16][40]: P, cols16..31 zero

  float mreg[2][4];
  #pragma unroll
  for (int pp = 0; pp < 2; ++pp) {
    int pair = wave * 2 + pp;
    #pragma unroll
    for (int r = 0; r < 4; ++r) {
      int row = fq * 4 + r;
      int Pg = mtile * 16 + pair * 2 + (row >> 3);
      mreg[pp][r] = mask[(size_t)Pg * 64 + (row & 7) * 8 + (fr & 7)];
    }
  }

  {  // zero-fill VT pad cols
    int d = t >> 2, q = t & 3;
    ushort4 z; z.x = 0; z.y = 0; z.z = 0; z.w = 0;
    *(ushort4*)(VT + d * 152 + 128 + q * 4) = z;
  }
  #pragma unroll
  for (int n = 0; n < 6; ++n) {
    int col = wn * 96 + n * 16 + fr;
    #pragma unroll
    for (int m = 0; m < 4; ++m) {
      if (col < 128) {
        unsigned short* T = (col < 64) ? Qs : Ks;
        unsigned cc = (unsigned)(col & 63);
        #pragma unroll
        for (int r = 0; r < 4; ++r) {
          int row = wm * 64 + m * 16 + fq * 4 + r;
          unsigned byte = (unsigned)row * 128 + ((cc * 2) ^ (((unsigned)(row & 7)) << 4));
          *(unsigned short*)((unsigned char*)T + byte) = f2bf(acc[m][n][r]);
        }
      } else {
        int d = col - 128;
        ushort4 p;
        p.x = f2bf(acc[m][n][0]); p.y = f2bf(acc[m][n][1]);
        p.z = f2bf(acc[m][n][2]); p.w = f2bf(acc[m][n][3]);
        *(ushort4*)(VT + d * 152 + (wm * 64 + m * 16 + fq * 4)) = p;
      }
    }
  }
  __syncthreads();

  #pragma unroll
  for (int pp = 0; pp < 2; ++pp) {
    const int pair = wave * 2 + pp;
    const unsigned rbyte = (unsigned)(pair * 16 + fr) * 128;
    const unsigned xrp = ((unsigned)(fr & 7)) << 4;
    f32x4 s = {0.f, 0.f, 0.f, 0.f};
    #pragma unroll
    for (int kk = 0; kk < 2; ++kk) {
      const unsigned ko = ((unsigned)(kk * 64 + fq * 16)) ^ xrp;
      bf16x8 qf = *(const bf16x8*)((unsigned char*)Qs + rbyte + ko);
      bf16x8 kf = *(const bf16x8*)((unsigned char*)Ks + rbyte + ko);
      s = __builtin_amdgcn_mfma_f32_16x16x32_bf16(qf, kf, s, 0, 0, 0);
    }
    float p4[4];
    #pragma unroll
    for (int r = 0; r < 4; ++r) {
      int row = fq * 4 + r;
      bool valid = (row >> 3) == (fr >> 3);
      p4[r] = valid ? s[r] * SCALE_ * mreg[pp][r] : -3.0e38f;
    }
    #pragma unroll
    for (int r = 0; r < 4; ++r) {
      float v = p4[r];
      float mx = v;
      mx = fmaxf(mx, __shfl_xor(mx, 1));
      mx = fmaxf(mx, __shfl_xor(mx, 2));
      mx = fmaxf(mx, __shfl_xor(mx, 4));
      float e = __expf(v - mx);
      float sm = e;
      sm += __shfl_xor(sm, 1);
      sm += __shfl_xor(sm, 2);
      sm += __shfl_xor(sm, 4);
      p4[r] = e / sm;
    }
    #pragma unroll
    for (int r = 0; r < 4; ++r) {
      int row = fq * 4 + r;
      bool valid = (row >> 3) == (fr >> 3);
      Pl[pair * 640 + row * 40 + fr] = valid ? f2bf(p4[r]) : (unsigned short)0;
      Pl[pair * 640 + row * 40 + 16 + fr] = 0;
    }
    #pragma unroll
    for (int dblk = 0; dblk < 4; ++dblk) {
      bf16x8 af = *(const bf16x8*)((unsigned char*)VT +
                    (unsigned)(dblk * 16 + fr) * 304 + (unsigned)(pair * 32 + fq * 16));
      bf16x8 bf = *(const bf16x8*)((unsigned char*)Pl +
                    (unsigned)pair * 1280 + (unsigned)fr * 80 + (unsigned)fq * 16);
      f32x4 o = {0.f, 0.f, 0.f, 0.f};
      o = __builtin_amdgcn_mfma_f32_16x16x32_bf16(af, bf, o, 0, 0, 0);
      ushort4 pk;
      pk.x = f2bf(o[0]); pk.y = f2bf(o[1]); pk.z = f2bf(o[2]); pk.w = f2bf(o[3]);
      *(ushort4*)(attn_out + (size_t)(r0 + pair * 16 + fr) * 512 +
                  head * 64 + dblk * 16 + fq * 4) = pk;
    }
  }
}

// ---------------- K2: out = attn @ woutT^T + bias (f32 out) ----------------
// 128x128 tile, dbuf GLL, counted vmcnt(8) + lgkmcnt(0) + raw barriers (round-12 proven).
__global__ __launch_bounds__(256, 2)
void outproj_kernel(const unsigned short* __restrict__ attn,
                    const unsigned short* __restrict__ woutT,
                    const float* __restrict__ bias,
                    float* __restrict__ out) {
  __shared__ __align__(16) unsigned char smem[65536];  // 2 x (A 16KB + B 16KB)
  const int t = threadIdx.x;
  const int lane = t & 63, wave = t >> 6;
  const int wm = wave >> 1, wn = wave & 1;
  const int fr = lane & 15, fq = lane >> 4;
  const int l8 = lane >> 3;
  const int cswz = ((lane & 7) ^ l8) * 8;

  const int per = gridDim.x >> 3;
  const int lin = (blockIdx.x & 7) * per + (blockIdx.x >> 3);
  const int mtile = lin >> 2, nt = lin & 3;
  const int r0 = mtile * 128, n0 = nt * 128;

  f32x4 acc[4][4];
  const f32x4 z4 = {0.f, 0.f, 0.f, 0.f};
  #pragma unroll
  for (int m = 0; m < 4; ++m)
    #pragma unroll
    for (int n = 0; n < 4; ++n) acc[m][n] = z4;

  auto STAGE = [&](int buf, int kt2) {   // exactly 8 GLL per wave
    unsigned char* base = smem + buf * 32768;
    const int k0 = kt2 * 64;
    const unsigned short* gA = attn  + (size_t)(r0 + l8) * 512 + k0 + cswz;
    const unsigned short* gB = woutT + (size_t)(n0 + l8) * 512 + k0 + cswz;
    #pragma unroll
    for (int i = 0; i < 4; ++i) {
      int c = wave * 4 + i;
      GLL16(gA + (size_t)c * 8 * 512, base + c * 1024);
      GLL16(gB + (size_t)c * 8 * 512, base + 16384 + c * 1024);
    }
  };

  STAGE(0, 0);
  for (int kt = 0; kt < 8; ++kt) {
    const int cur = kt & 1;
    if (kt < 7) {
      STAGE(cur ^ 1, kt + 1);
      VMCNT(8);
    } else {
      VMCNT(0);
    }
    __builtin_amdgcn_s_barrier();
    unsigned char* Ab = smem + cur * 32768;
    unsigned char* Bb = Ab + 16384;
    const unsigned xr = ((unsigned)(fr & 7)) << 4;
    #pragma unroll
    for (int kk = 0; kk < 2; ++kk) {
      const unsigned ko = ((unsigned)(kk * 64 + fq * 16)) ^ xr;
      bf16x8 a[4], b[4];
      #pragma unroll
      for (int m = 0; m < 4; ++m)
        a[m] = *(const bf16x8*)(Ab + (unsigned)(wm * 64 + m * 16 + fr) * 128 + ko);
      #pragma unroll
      for (int n = 0; n < 4; ++n)
        b[n] = *(const bf16x8*)(Bb + (unsigned)(wn * 64 + n * 16 + fr) * 128 + ko);
      __builtin_amdgcn_s_setprio(1);
      #pragma unroll
      for (int m = 0; m < 4; ++m)
        #pragma unroll
        for (int n = 0; n < 4; ++n)
          acc[m][n] = __builtin_amdgcn_mfma_f32_16x16x32_bf16(a[m], b[n], acc[m][n], 0, 0, 0);
      __builtin_amdgcn_s_setprio(0);
    }
    LGKM0;
    __builtin_amdgcn_s_barrier();
  }
  __builtin_amdgcn_sched_barrier(0);

  #pragma unroll
  for (int n = 0; n < 4; ++n) {
    int col = n0 + wn * 64 + n * 16 + fr;
    float bv = bias[col];
    #pragma unroll
    for (int m = 0; m < 4; ++m) {
      #pragma unroll
      for (int j = 0; j < 4; ++j) {
        int row = r0 + wm * 64 + m * 16 + fq * 4 + j;
        out[(size_t)row * 512 + col] = acc[m][n][j] + bv;
      }
    }
  }
}

extern "C" void kernel_launch(void* const* d_in, const int* in_sizes, int n_in,
                              void* d_out, int out_size, void* d_ws, size_t ws_size,
                              hipStream_t stream) {
  const float* x    = (const float*)d_in[0];  // [65536][512]
  const float* mask = (const float*)d_in[1];  // [8192][8][8]
  const float* wqkv = (const float*)d_in[2];  // [512][1536]
  const float* wout = (const float*)d_in[3];  // [512][512]
  const float* bias = (const float*)d_in[4];  // [512]
  float* out = (float*)d_out;

  // ws: attn bf16 64MB | wqkvT 1.5MB | woutT 0.5MB  (66MB; xb eliminated)
  unsigned char* ws = (unsigned char*)d_ws;
  unsigned short* attn  = (unsigned short*)ws;
  unsigned short* wqkvT = (unsigned short*)(ws + 67108864);
  unsigned short* woutT = (unsigned short*)(ws + 67108864 + 1572864);

  prep_w_kernel<<<4096, 256, 0, stream>>>(wqkv, wout, wqkvT, woutT);
  qkv_attn_kernel<<<4096, 256, 0, stream>>>(x, mask, wqkvT, attn);
  outproj_kernel<<<2048, 256, 0, stream>>>(attn, woutT, bias, out);
}

// Round 14
// 226.202 us; speedup vs baseline: 1.2624x; 1.2624x over previous
//
#include <hip/hip_runtime.h>
#include <hip/hip_bf16.h>

#define NROWS 65536   // B*H*W*n
#define DIM   512
#define SCALE_ 0.125f // 64^-0.5

typedef short bf16x8 __attribute__((ext_vector_type(8)));
typedef unsigned short u16x8 __attribute__((ext_vector_type(8)));
typedef float f32x4 __attribute__((ext_vector_type(4)));

__device__ __forceinline__ unsigned short f2bf(float f) {
  union { float f; unsigned u; } v; v.f = f;
  unsigned r = v.u + 0x7FFFu + ((v.u >> 16) & 1u);  // RNE
  return (unsigned short)(r >> 16);
}

// async global->LDS, 16B per lane. LDS dest is wave-uniform base + lane*16 (HW).
#define GLL16(gptr, lptr) \
  __builtin_amdgcn_global_load_lds((const __attribute__((address_space(1))) void*)(gptr), \
                                   (__attribute__((address_space(3))) void*)(lptr), 16, 0, 0)
#define VMCNT(n) asm volatile("s_waitcnt vmcnt(" #n ")" ::: "memory")
#define LGKM0    asm volatile("s_waitcnt lgkmcnt(0)" ::: "memory")

// ---------------- prep: x f32->bf16 (blocks 0..16383) + weights transpose (16384..20479) ----
__global__ void prep_kernel(const float* __restrict__ x,
                            const float* __restrict__ wqkv,
                            const float* __restrict__ wout,
                            unsigned short* __restrict__ xb,
                            unsigned short* __restrict__ wqkvT,
                            unsigned short* __restrict__ woutT) {
  if (blockIdx.x < 16384) {
    size_t i = ((size_t)blockIdx.x * 256 + threadIdx.x) * 8;
    float4 a = *(const float4*)(x + i);
    float4 b = *(const float4*)(x + i + 4);
    u16x8 p;
    p[0] = f2bf(a.x); p[1] = f2bf(a.y); p[2] = f2bf(a.z); p[3] = f2bf(a.w);
    p[4] = f2bf(b.x); p[5] = f2bf(b.y); p[6] = f2bf(b.z); p[7] = f2bf(b.w);
    *(u16x8*)(xb + i) = p;
  } else {
    int idx = (blockIdx.x - 16384) * 256 + threadIdx.x;
    if (idx < 1536 * 512) {
      int j = idx >> 9, c = idx & 511;
      wqkvT[idx] = f2bf(wqkv[(size_t)c * 1536 + j]);
    } else {
      int k2 = idx - 1536 * 512;
      int n = k2 >> 9, c = k2 & 511;
      woutT[k2] = f2bf(wout[(size_t)c * 512 + n]);
    }
  }
}

// ---------------- K1: fused QKV GEMM + attention (round-10/12 proven) ----------------
// grid 4096 = 512 mtiles x 8 heads. 256 thr (4 waves 2x2), tile 128x192, BK=64.
// A,B via global_load_lds (pre-swizzled source), dbuf.
// Counted vmcnt(10) BEFORE compute; lgkmcnt(0) before end barrier (race fix).
// s_setprio around MFMA clusters (measured null, kept: zero cost).
__global__ __launch_bounds__(256, 2)
void qkv_attn_kernel(const unsigned short* __restrict__ xb,
                     const float* __restrict__ mask,
                     const unsigned short* __restrict__ wqkvT,
                     unsigned short* __restrict__ attn_out) {
  // GEMM: dbuf, buf = A[128][64swz] 16KB + B[192][64swz] 24KB = 40KB -> 80KB.
  // Epilogue union: Qs[128][64]swz @0 | Ks @16384 | VT[64][152] @32768 | Pl @52224.
  __shared__ __align__(16) unsigned char smem[81920];

  const int t = threadIdx.x;
  const int lane = t & 63, wave = t >> 6;
  const int wm = wave >> 1, wn = wave & 1;
  const int fr = lane & 15, fq = lane >> 4;
  const int l8 = lane >> 3;
  const int cswz = ((lane & 7) ^ l8) * 8;   // inverse-swizzled source col (bf16 units)

  const int per = gridDim.x >> 3;
  const int lin = (blockIdx.x & 7) * per + (blockIdx.x >> 3);
  const int mtile = lin >> 3, head = lin & 7;
  const int r0 = mtile * 128;

  f32x4 acc[4][6];
  const f32x4 z4 = {0.f, 0.f, 0.f, 0.f};
  #pragma unroll
  for (int m = 0; m < 4; ++m)
    #pragma unroll
    for (int n = 0; n < 6; ++n) acc[m][n] = z4;

  auto STAGE = [&](int buf, int kt2) {   // exactly 10 GLL per wave (4 A + 6 B)
    unsigned char* base = smem + buf * 40960;
    const int k0 = kt2 * 64;
    const unsigned short* gA = xb + (size_t)(r0 + l8) * 512 + k0 + cswz;
    #pragma unroll
    for (int i = 0; i < 4; ++i) {
      int c = wave * 4 + i;
      GLL16(gA + (size_t)c * 8 * 512, base + c * 1024);
    }
    const unsigned short* gB = wqkvT + k0 + cswz;
    #pragma unroll
    for (int i = 0; i < 6; ++i) {
      int c = wave * 6 + i;
      int n = c * 8 + l8;
      int jg = ((n >> 6) << 9) + head * 64 + (n & 63);
      GLL16(gB + (size_t)jg * 512, base + 16384 + c * 1024);
    }
  };

  STAGE(0, 0);
  for (int kt = 0; kt < 8; ++kt) {
    const int cur = kt & 1;
    if (kt < 7) {
      STAGE(cur ^ 1, kt + 1);   // 10 newer ops in flight...
      VMCNT(10);                // ...so this retires exactly tile kt's 10
    } else {
      VMCNT(0);
    }
    __builtin_amdgcn_s_barrier();      // publish tile kt block-wide
    unsigned char* Ab = smem + cur * 40960;
    unsigned char* Bb = Ab + 16384;
    const unsigned xr = ((unsigned)(fr & 7)) << 4;
    #pragma unroll
    for (int kk = 0; kk < 2; ++kk) {
      const unsigned ko = ((unsigned)(kk * 64 + fq * 16)) ^ xr;
      bf16x8 a[4], b[6];
      #pragma unroll
      for (int m = 0; m < 4; ++m)
        a[m] = *(const bf16x8*)(Ab + (unsigned)(wm * 64 + m * 16 + fr) * 128 + ko);
      #pragma unroll
      for (int n = 0; n < 6; ++n)
        b[n] = *(const bf16x8*)(Bb + (unsigned)(wn * 96 + n * 16 + fr) * 128 + ko);
      __builtin_amdgcn_s_setprio(1);
      #pragma unroll
      for (int m = 0; m < 4; ++m)
        #pragma unroll
        for (int n = 0; n < 6; ++n)
          acc[m][n] = __builtin_amdgcn_mfma_f32_16x16x32_bf16(a[m], b[n], acc[m][n], 0, 0, 0);
      __builtin_amdgcn_s_setprio(0);
    }
    LGKM0;                             // all ds_reads retired (regs latched)...
    __builtin_amdgcn_s_barrier();      // ...before any wave may overwrite this buffer
  }
  __builtin_amdgcn_sched_barrier(0);   // keep epilogue vmem out of the counted loop

  // ---------------- epilogue (proven structure) ----------------
  unsigned short* Qs = (unsigned short*)smem;             // [128][64] bf16, XOR-swz
  unsigned short* Ks = (unsigned short*)(smem + 16384);   // [128][64]
  unsigned short* VT = (unsigned short*)(smem + 32768);   // [64][152]: V^T, cols128..143 zero
  unsigned short* Pl = (unsigned short*)(smem + 52224);   // [8][16][40]: P, cols16..31 zero

  // mask preload after the counted loop; latency hides under the spill.
  float mreg[2][4];
  #pragma unroll
  for (int pp = 0; pp < 2; ++pp) {
    int pair = wave * 2 + pp;
    #pragma unroll
    for (int r = 0; r < 4; ++r) {
      int row = fq * 4 + r;
      int Pg = mtile * 16 + pair * 2 + (row >> 3);
      mreg[pp][r] = mask[(size_t)Pg * 64 + (row & 7) * 8 + (fr & 7)];
    }
  }

  {  // zero-fill VT pad cols
    int d = t >> 2, q = t & 3;
    ushort4 z; z.x = 0; z.y = 0; z.z = 0; z.w = 0;
    *(ushort4*)(VT + d * 152 + 128 + q * 4) = z;
  }
  #pragma unroll
  for (int n = 0; n < 6; ++n) {
    int col = wn * 96 + n * 16 + fr;
    #pragma unroll
    for (int m = 0; m < 4; ++m) {
      if (col < 128) {
        unsigned short* T = (col < 64) ? Qs : Ks;
        unsigned cc = (unsigned)(col & 63);
        #pragma unroll
        for (int r = 0; r < 4; ++r) {
          int row = wm * 64 + m * 16 + fq * 4 + r;
          unsigned byte = (unsigned)row * 128 + ((cc * 2) ^ (((unsigned)(row & 7)) << 4));
          *(unsigned short*)((unsigned char*)T + byte) = f2bf(acc[m][n][r]);
        }
      } else {
        int d = col - 128;
        ushort4 p;
        p.x = f2bf(acc[m][n][0]); p.y = f2bf(acc[m][n][1]);
        p.z = f2bf(acc[m][n][2]); p.w = f2bf(acc[m][n][3]);
        *(ushort4*)(VT + d * 152 + (wm * 64 + m * 16 + fq * 4)) = p;
      }
    }
  }
  __syncthreads();

  #pragma unroll
  for (int pp = 0; pp < 2; ++pp) {
    const int pair = wave * 2 + pp;
    const unsigned rbyte = (unsigned)(pair * 16 + fr) * 128;
    const unsigned xrp = ((unsigned)(fr & 7)) << 4;
    // dots: S = Q . K^T (16x16; cross-pixel entries masked below)
    f32x4 s = {0.f, 0.f, 0.f, 0.f};
    #pragma unroll
    for (int kk = 0; kk < 2; ++kk) {
      const unsigned ko = ((unsigned)(kk * 64 + fq * 16)) ^ xrp;
      bf16x8 qf = *(const bf16x8*)((unsigned char*)Qs + rbyte + ko);
      bf16x8 kf = *(const bf16x8*)((unsigned char*)Ks + rbyte + ko);
      s = __builtin_amdgcn_mfma_f32_16x16x32_bf16(qf, kf, s, 0, 0, 0);
    }
    float p4[4];
    #pragma unroll
    for (int r = 0; r < 4; ++r) {
      int row = fq * 4 + r;
      bool valid = (row >> 3) == (fr >> 3);
      p4[r] = valid ? s[r] * SCALE_ * mreg[pp][r] : -3.0e38f;
    }
    #pragma unroll
    for (int r = 0; r < 4; ++r) {
      float v = p4[r];
      float mx = v;
      mx = fmaxf(mx, __shfl_xor(mx, 1));
      mx = fmaxf(mx, __shfl_xor(mx, 2));
      mx = fmaxf(mx, __shfl_xor(mx, 4));
      float e = __expf(v - mx);
      float sm = e;
      sm += __shfl_xor(sm, 1);
      sm += __shfl_xor(sm, 2);
      sm += __shfl_xor(sm, 4);
      p4[r] = e / sm;
    }
    #pragma unroll
    for (int r = 0; r < 4; ++r) {
      int row = fq * 4 + r;
      bool valid = (row >> 3) == (fr >> 3);
      Pl[pair * 640 + row * 40 + fr] = valid ? f2bf(p4[r]) : (unsigned short)0;
      Pl[pair * 640 + row * 40 + 16 + fr] = 0;
    }
    // PV: D[d][qi] = VT[d][j] . P[qi][j]
    #pragma unroll
    for (int dblk = 0; dblk < 4; ++dblk) {
      bf16x8 af = *(const bf16x8*)((unsigned char*)VT +
                    (unsigned)(dblk * 16 + fr) * 304 + (unsigned)(pair * 32 + fq * 16));
      bf16x8 bf = *(const bf16x8*)((unsigned char*)Pl +
                    (unsigned)pair * 1280 + (unsigned)fr * 80 + (unsigned)fq * 16);
      f32x4 o = {0.f, 0.f, 0.f, 0.f};
      o = __builtin_amdgcn_mfma_f32_16x16x32_bf16(af, bf, o, 0, 0, 0);
      ushort4 pk;
      pk.x = f2bf(o[0]); pk.y = f2bf(o[1]); pk.z = f2bf(o[2]); pk.w = f2bf(o[3]);
      *(ushort4*)(attn_out + (size_t)(r0 + pair * 16 + fr) * 512 +
                  head * 64 + dblk * 16 + fq * 4) = pk;
    }
  }
}

// ---------------- K2: out = attn @ woutT^T + bias (f32 out) ----------------
// 128x128 tile, dbuf GLL. Counted vmcnt(8) + lgkmcnt(0) + raw barriers.
__global__ __launch_bounds__(256, 2)
void outproj_kernel(const unsigned short* __restrict__ attn,
                    const unsigned short* __restrict__ woutT,
                    const float* __restrict__ bias,
                    float* __restrict__ out) {
  __shared__ __align__(16) unsigned char smem[65536];  // 2 x (A 16KB + B 16KB)
  const int t = threadIdx.x;
  const int lane = t & 63, wave = t >> 6;
  const int wm = wave >> 1, wn = wave & 1;
  const int fr = lane & 15, fq = lane >> 4;
  const int l8 = lane >> 3;
  const int cswz = ((lane & 7) ^ l8) * 8;

  const int per = gridDim.x >> 3;
  const int lin = (blockIdx.x & 7) * per + (blockIdx.x >> 3);
  const int mtile = lin >> 2, nt = lin & 3;
  const int r0 = mtile * 128, n0 = nt * 128;

  f32x4 acc[4][4];
  const f32x4 z4 = {0.f, 0.f, 0.f, 0.f};
  #pragma unroll
  for (int m = 0; m < 4; ++m)
    #pragma unroll
    for (int n = 0; n < 4; ++n) acc[m][n] = z4;

  auto STAGE = [&](int buf, int kt2) {   // exactly 8 GLL per wave
    unsigned char* base = smem + buf * 32768;
    const int k0 = kt2 * 64;
    const unsigned short* gA = attn  + (size_t)(r0 + l8) * 512 + k0 + cswz;
    const unsigned short* gB = woutT + (size_t)(n0 + l8) * 512 + k0 + cswz;
    #pragma unroll
    for (int i = 0; i < 4; ++i) {
      int c = wave * 4 + i;
      GLL16(gA + (size_t)c * 8 * 512, base + c * 1024);
      GLL16(gB + (size_t)c * 8 * 512, base + 16384 + c * 1024);
    }
  };

  STAGE(0, 0);
  for (int kt = 0; kt < 8; ++kt) {
    const int cur = kt & 1;
    if (kt < 7) {
      STAGE(cur ^ 1, kt + 1);   // 8 newer in flight...
      VMCNT(8);                 // ...retires exactly tile kt's 8
    } else {
      VMCNT(0);
    }
    __builtin_amdgcn_s_barrier();
    unsigned char* Ab = smem + cur * 32768;
    unsigned char* Bb = Ab + 16384;
    const unsigned xr = ((unsigned)(fr & 7)) << 4;
    #pragma unroll
    for (int kk = 0; kk < 2; ++kk) {
      const unsigned ko = ((unsigned)(kk * 64 + fq * 16)) ^ xr;
      bf16x8 a[4], b[4];
      #pragma unroll
      for (int m = 0; m < 4; ++m)
        a[m] = *(const bf16x8*)(Ab + (unsigned)(wm * 64 + m * 16 + fr) * 128 + ko);
      #pragma unroll
      for (int n = 0; n < 4; ++n)
        b[n] = *(const bf16x8*)(Bb + (unsigned)(wn * 64 + n * 16 + fr) * 128 + ko);
      __builtin_amdgcn_s_setprio(1);
      #pragma unroll
      for (int m = 0; m < 4; ++m)
        #pragma unroll
        for (int n = 0; n < 4; ++n)
          acc[m][n] = __builtin_amdgcn_mfma_f32_16x16x32_bf16(a[m], b[n], acc[m][n], 0, 0, 0);
      __builtin_amdgcn_s_setprio(0);
    }
    LGKM0;
    __builtin_amdgcn_s_barrier();
  }
  __builtin_amdgcn_sched_barrier(0);   // keep epilogue vmem out of the counted loop

  #pragma unroll
  for (int n = 0; n < 4; ++n) {
    int col = n0 + wn * 64 + n * 16 + fr;
    float bv = bias[col];
    #pragma unroll
    for (int m = 0; m < 4; ++m) {
      #pragma unroll
      for (int j = 0; j < 4; ++j) {
        int row = r0 + wm * 64 + m * 16 + fq * 4 + j;
        out[(size_t)row * 512 + col] = acc[m][n][j] + bv;
      }
    }
  }
}

extern "C" void kernel_launch(void* const* d_in, const int* in_sizes, int n_in,
                              void* d_out, int out_size, void* d_ws, size_t ws_size,
                              hipStream_t stream) {
  const float* x    = (const float*)d_in[0];  // [65536][512]
  const float* mask = (const float*)d_in[1];  // [8192][8][8]
  const float* wqkv = (const float*)d_in[2];  // [512][1536]
  const float* wout = (const float*)d_in[3];  // [512][512]
  const float* bias = (const float*)d_in[4];  // [512]
  float* out = (float*)d_out;

  // ws: attn bf16 64MB | wqkvT 1.5MB | woutT 0.5MB | xb bf16 64MB (133.2MB, proven)
  unsigned char* ws = (unsigned char*)d_ws;
  unsigned short* attn  = (unsigned short*)ws;
  unsigned short* wqkvT = (unsigned short*)(ws + 67108864);
  unsigned short* woutT = (unsigned short*)(ws + 67108864 + 1572864);
  unsigned short* xb    = (unsigned short*)(ws + 67108864 + 1572864 + 524288);

  prep_kernel<<<20480, 256, 0, stream>>>(x, wqkv, wout, xb, wqkvT, woutT);
  qkv_attn_kernel<<<4096, 256, 0, stream>>>(xb, mask, wqkvT, attn);
  outproj_kernel<<<2048, 256, 0, stream>>>(attn, woutT, bias, out);
}